// Round 1
// baseline (520.571 us; speedup 1.0000x reference)
//
#include <hip/hip_runtime.h>
#include <hip/hip_bf16.h>

// ---------------------------------------------------------------------------
// ATTEfficient: s = tanh(X@Ww^T + bw)@v ; segment softmax ; att-pool ; MLP head
// X: [32768,1280] f32, Ww: [1280,1280], v: [1280], W1: [512,1280], W2: [1,512]
// ---------------------------------------------------------------------------

#define TOTAL_ROWS 32768
#define DIM 1280
#define NSEG 128
#define DHEAD 512

typedef _Float16 f16x8 __attribute__((ext_vector_type(8)));
typedef float f32x4 __attribute__((ext_vector_type(4)));

// ---- workspace layout (bytes) ----
#define OFF_XH   0                            // 32768*1280*2 = 83886080
#define OFF_WH   83886080                     // 1280*1280*2  = 3276800
#define OFF_S    87162880                     // 32768*4      = 131072
#define OFF_ATT  87293952                     // 32768*4      = 131072
#define OFF_SEG  87425024                     // 132*4 -> pad 1024
#define OFF_POOL 87426048                     // 128*1280*4   = 655360
#define OFF_H    88081408                     // 128*512*4    = 262144
// total ~88.3 MB

__device__ __forceinline__ void load_lds16(const void* g, void* l) {
  __builtin_amdgcn_global_load_lds(
      (const __attribute__((address_space(1))) unsigned int*)g,
      (__attribute__((address_space(3))) unsigned int*)l, 16, 0, 0);
}

__device__ __forceinline__ float tanh_fast(float x) {
  // tanh(x) = 1 - 2/(e^{2x}+1); exact algebraically, ~1e-6 rel err via v_exp/v_rcp
  float e = __expf(2.0f * x);
  return 1.0f - 2.0f * __builtin_amdgcn_rcpf(e + 1.0f);
}

// ---- f32 -> f16 conversion, 8 elems/thread ----
__global__ void cvt_f16_kernel(const float* __restrict__ in,
                               _Float16* __restrict__ out, int n8) {
  int i = blockIdx.x * blockDim.x + threadIdx.x;
  if (i >= n8) return;
  const float4* p = (const float4*)in + (size_t)i * 2;
  float4 u0 = p[0], u1 = p[1];
  f16x8 h;
  h[0] = (_Float16)u0.x; h[1] = (_Float16)u0.y;
  h[2] = (_Float16)u0.z; h[3] = (_Float16)u0.w;
  h[4] = (_Float16)u1.x; h[5] = (_Float16)u1.y;
  h[6] = (_Float16)u1.z; h[7] = (_Float16)u1.w;
  *((f16x8*)out + i) = h;
}

// ---- segment boundaries from sorted segment_ids ----
__global__ void segstart_kernel(const int* __restrict__ sid,
                                int* __restrict__ segstart, int total) {
  int i = blockIdx.x * blockDim.x + threadIdx.x;
  if (i >= total) return;
  int sg = sid[i];
  if (i == 0) segstart[0] = 0;
  else if (sid[i - 1] != sg) segstart[sg] = i;
  if (i == total - 1) segstart[sg + 1] = total;
}

// ---- fused GEMM + tanh + dot-with-v:  s[i] += sum_j tanh(X_i.W_j + bw_j) v_j
// grid (256 row-blocks, 10 j-tiles), block 256 (4 waves, 2x2), tile 128x128xBK32
__global__ __launch_bounds__(256) void gemm_s_kernel(
    const _Float16* __restrict__ X, const _Float16* __restrict__ W,
    const float* __restrict__ v, const float* __restrict__ bw,
    float* __restrict__ s) {
  __shared__ _Float16 As[128 * 32];
  __shared__ _Float16 Bs[128 * 32];
  const int rowBase = blockIdx.x * 128;
  const int jBase = blockIdx.y * 128;
  const int t = threadIdx.x;
  const int lane = t & 63;
  const int w = t >> 6;
  const int wm = w & 1, wn = w >> 1;

  f32x4 acc[4][4];
  const f32x4 zero = {0.f, 0.f, 0.f, 0.f};
#pragma unroll
  for (int i = 0; i < 4; ++i)
#pragma unroll
    for (int j = 0; j < 4; ++j) acc[i][j] = zero;

  for (int k0 = 0; k0 < DIM; k0 += 32) {
    __syncthreads();
#pragma unroll
    for (int q = 0; q < 2; ++q) {
      // chunk c covers 16B; tile row = c>>2 (32 f16 = 64B = 4 chunks/row)
      int c = w * 128 + q * 64 + lane;
      int row = c >> 2, c16 = c & 3;
      // LDS dest: wave-uniform base; HW scatters lane i at base + i*16
      load_lds16(X + (size_t)(rowBase + row) * DIM + k0 + c16 * 8,
                 &As[(size_t)(w * 128 + q * 64) * 8]);
      load_lds16(W + (size_t)(jBase + row) * DIM + k0 + c16 * 8,
                 &Bs[(size_t)(w * 128 + q * 64) * 8]);
    }
    __syncthreads();

    f16x8 a[4], b[4];
    const int kb = (lane >> 4) * 8;
#pragma unroll
    for (int mt = 0; mt < 4; ++mt)
      a[mt] = *(const f16x8*)&As[(wm * 64 + mt * 16 + (lane & 15)) * 32 + kb];
#pragma unroll
    for (int nt = 0; nt < 4; ++nt)
      b[nt] = *(const f16x8*)&Bs[(wn * 64 + nt * 16 + (lane & 15)) * 32 + kb];
#pragma unroll
    for (int mt = 0; mt < 4; ++mt)
#pragma unroll
      for (int nt = 0; nt < 4; ++nt)
        acc[mt][nt] =
            __builtin_amdgcn_mfma_f32_16x16x32_f16(a[mt], b[nt], acc[mt][nt], 0, 0, 0);
  }

  // epilogue: C/D layout col=lane&15, row=(lane>>4)*4+reg
  const int colBase = jBase + wn * 64 + (lane & 15);
  float vv[4], bb[4];
#pragma unroll
  for (int nt = 0; nt < 4; ++nt) {
    int j = colBase + nt * 16;
    vv[nt] = v[j];
    bb[nt] = bw[j];
  }
  const int g = lane >> 4;
#pragma unroll
  for (int mt = 0; mt < 4; ++mt) {
#pragma unroll
    for (int r = 0; r < 4; ++r) {
      float sumv = 0.f;
#pragma unroll
      for (int nt = 0; nt < 4; ++nt)
        sumv += tanh_fast(acc[mt][nt][r] + bb[nt]) * vv[nt];
      // reduce across the 16 lanes sharing (lane>>4): cols of this wave-half
      sumv += __shfl_xor(sumv, 1);
      sumv += __shfl_xor(sumv, 2);
      sumv += __shfl_xor(sumv, 4);
      sumv += __shfl_xor(sumv, 8);
      if ((lane & 15) == 0) {
        int row = rowBase + wm * 64 + mt * 16 + g * 4 + r;
        atomicAdd(&s[row], sumv);
      }
    }
  }
}

// ---- per-segment stable softmax -> att ----
__global__ void softmax_kernel(const float* __restrict__ s,
                               const int* __restrict__ segstart,
                               float* __restrict__ att) {
  int seg = blockIdx.x;
  int st = segstart[seg], en = segstart[seg + 1];
  int t = threadIdx.x;
  __shared__ float red[8];
  float m = -1e30f;
  for (int i = st + t; i < en; i += 256) m = fmaxf(m, s[i]);
  for (int d = 1; d < 64; d <<= 1) m = fmaxf(m, __shfl_xor(m, d));
  if ((t & 63) == 0) red[t >> 6] = m;
  __syncthreads();
  m = fmaxf(fmaxf(red[0], red[1]), fmaxf(red[2], red[3]));
  float z = 0.f;
  for (int i = st + t; i < en; i += 256) z += __expf(s[i] - m);
  for (int d = 1; d < 64; d <<= 1) z += __shfl_xor(z, d);
  if ((t & 63) == 0) red[4 + (t >> 6)] = z;
  __syncthreads();
  z = red[4] + red[5] + red[6] + red[7];
  float rz = 1.0f / z;
  for (int i = st + t; i < en; i += 256) att[i] = __expf(s[i] - m) * rz;
}

// ---- attention-weighted pooling: pooled[seg][col] = sum att[r]*F[r][col] ----
// grid (5 col-chunks of 256, 128 segs), block 256
__global__ void pool_kernel(const float* __restrict__ F,
                            const float* __restrict__ att,
                            const int* __restrict__ segstart,
                            float* __restrict__ pooled) {
  int seg = blockIdx.y;
  int col = blockIdx.x * 256 + threadIdx.x;
  int st = segstart[seg], en = segstart[seg + 1];
  float acc = 0.f;
  int r = st;
  for (; r + 4 <= en; r += 4) {
    acc = fmaf(att[r], F[(size_t)r * DIM + col], acc);
    acc = fmaf(att[r + 1], F[(size_t)(r + 1) * DIM + col], acc);
    acc = fmaf(att[r + 2], F[(size_t)(r + 2) * DIM + col], acc);
    acc = fmaf(att[r + 3], F[(size_t)(r + 3) * DIM + col], acc);
  }
  for (; r < en; ++r) acc = fmaf(att[r], F[(size_t)r * DIM + col], acc);
  pooled[(size_t)seg * DIM + col] = acc;
}

// ---- head layer 1: h = relu(pooled @ W1^T + b1), [128,512] ----
// grid (32 o-groups of 16, 4 seg-groups of 32), block 256 = 16(tx=o) x 16(ty)
__global__ void head1_kernel(const float* __restrict__ pooled,
                             const float* __restrict__ W1,
                             const float* __restrict__ b1, float* __restrict__ h) {
  int og = blockIdx.x, sg = blockIdx.y;
  __shared__ float Wt[16 * 65];
  __shared__ float Pt[32 * 65];
  int t = threadIdx.x;
  int tx = t & 15, ty = t >> 4;
  float acc0 = 0.f, acc1 = 0.f;
  for (int kc = 0; kc < 20; ++kc) {
    __syncthreads();
#pragma unroll
    for (int u = 0; u < 4; ++u) {
      int lin = t + 256 * u;
      int o = lin >> 6, kk = lin & 63;
      Wt[o * 65 + kk] = W1[(size_t)(og * 16 + o) * DIM + kc * 64 + kk];
    }
#pragma unroll
    for (int u = 0; u < 8; ++u) {
      int lin = t + 256 * u;
      int ss = lin >> 6, kk = lin & 63;
      Pt[ss * 65 + kk] = pooled[(size_t)(sg * 32 + ss) * DIM + kc * 64 + kk];
    }
    __syncthreads();
#pragma unroll
    for (int kk = 0; kk < 64; ++kk) {
      float wv = Wt[tx * 65 + kk];
      acc0 = fmaf(Pt[ty * 65 + kk], wv, acc0);
      acc1 = fmaf(Pt[(ty + 16) * 65 + kk], wv, acc1);
    }
  }
  int o = og * 16 + tx;
  float bias = b1[o];
  h[(size_t)(sg * 32 + ty) * DHEAD + o] = fmaxf(acc0 + bias, 0.f);
  h[(size_t)(sg * 32 + ty + 16) * DHEAD + o] = fmaxf(acc1 + bias, 0.f);
}

// ---- head layer 2: out[seg] = relu_h[seg] . W2 + b2 ----
__global__ void head2_kernel(const float* __restrict__ h,
                             const float* __restrict__ W2,
                             const float* __restrict__ b2, float* __restrict__ out) {
  int seg = blockIdx.x;
  int t = threadIdx.x;
  float val = h[(size_t)seg * DHEAD + t] * W2[t] +
              h[(size_t)seg * DHEAD + t + 256] * W2[t + 256];
  for (int d = 1; d < 64; d <<= 1) val += __shfl_xor(val, d);
  __shared__ float red[4];
  if ((t & 63) == 0) red[t >> 6] = val;
  __syncthreads();
  if (t == 0) out[seg] = red[0] + red[1] + red[2] + red[3] + b2[0];
}

extern "C" void kernel_launch(void* const* d_in, const int* in_sizes, int n_in,
                              void* d_out, int out_size, void* d_ws, size_t ws_size,
                              hipStream_t stream) {
  const float* features = (const float*)d_in[0];
  const float* Ww = (const float*)d_in[1];
  const float* bw = (const float*)d_in[2];
  const float* v = (const float*)d_in[3];
  const float* W1 = (const float*)d_in[4];
  const float* b1 = (const float*)d_in[5];
  const float* W2 = (const float*)d_in[6];
  const float* b2 = (const float*)d_in[7];
  const int* segids = (const int*)d_in[8];
  float* out = (float*)d_out;

  char* ws = (char*)d_ws;
  _Float16* Xh = (_Float16*)(ws + OFF_XH);
  _Float16* Wh = (_Float16*)(ws + OFF_WH);
  float* s = (float*)(ws + OFF_S);
  float* att = (float*)(ws + OFF_ATT);
  int* segstart = (int*)(ws + OFF_SEG);
  float* pooled = (float*)(ws + OFF_POOL);
  float* h = (float*)(ws + OFF_H);

  // s is accumulated with atomics across j-tiles: zero it (ws is 0xAA-poisoned)
  hipMemsetAsync(s, 0, TOTAL_ROWS * sizeof(float), stream);

  cvt_f16_kernel<<<20480, 256, 0, stream>>>(features, Xh, TOTAL_ROWS * DIM / 8);
  cvt_f16_kernel<<<800, 256, 0, stream>>>(Ww, Wh, DIM * DIM / 8);
  segstart_kernel<<<TOTAL_ROWS / 256, 256, 0, stream>>>(segids, segstart, TOTAL_ROWS);

  dim3 ggrid(TOTAL_ROWS / 128, DIM / 128);  // x-major: all row-blocks of a j-tile first
  gemm_s_kernel<<<ggrid, 256, 0, stream>>>(Xh, Wh, v, bw, s);

  softmax_kernel<<<NSEG, 256, 0, stream>>>(s, segstart, att);
  pool_kernel<<<dim3(DIM / 256, NSEG), 256, 0, stream>>>(features, att, segstart, pooled);
  head1_kernel<<<dim3(32, 4), 256, 0, stream>>>(pooled, W1, b1, h);
  head2_kernel<<<NSEG, 256, 0, stream>>>(h, W2, b2, out);
}

// Round 2
// 479.967 us; speedup vs baseline: 1.0846x; 1.0846x over previous
//
#include <hip/hip_runtime.h>
#include <hip/hip_bf16.h>

// ---------------------------------------------------------------------------
// ATTEfficient: s = tanh(X@Ww^T + bw)@v ; segment softmax ; att-pool ; MLP head
// X: [32768,1280] f32, Ww: [1280,1280], v: [1280], W1: [512,1280], W2: [1,512]
// ---------------------------------------------------------------------------

#define TOTAL_ROWS 32768
#define DIM 1280
#define NSEG 128
#define DHEAD 512

typedef _Float16 f16x8 __attribute__((ext_vector_type(8)));
typedef float f32x4 __attribute__((ext_vector_type(4)));

// ---- workspace layout (bytes) ----  (identical to round 1 — known to fit)
#define OFF_XH   0                            // 32768*1280*2 = 83886080
#define OFF_WH   83886080                     // 1280*1280*2  = 3276800
#define OFF_S    87162880                     // 32768*4      = 131072
#define OFF_ATT  87293952                     // 32768*4      = 131072
#define OFF_SEG  87425024                     // 132*4 -> pad 1024
#define OFF_POOL 87426048                     // 128*1280*4   = 655360
#define OFF_H    88081408                     // 128*512*4    = 262144

__device__ __forceinline__ void load_lds16(const void* g, void* l) {
  __builtin_amdgcn_global_load_lds(
      (const __attribute__((address_space(1))) unsigned int*)g,
      (__attribute__((address_space(3))) unsigned int*)l, 16, 0, 0);
}

__device__ __forceinline__ float tanh_fast(float x) {
  float e = __expf(2.0f * x);
  return 1.0f - 2.0f * __builtin_amdgcn_rcpf(e + 1.0f);
}

// ---- f32 -> f16 conversion, 8 elems/thread ----
__global__ void cvt_f16_kernel(const float* __restrict__ in,
                               _Float16* __restrict__ out, int n8) {
  int i = blockIdx.x * blockDim.x + threadIdx.x;
  if (i >= n8) return;
  const float4* p = (const float4*)in + (size_t)i * 2;
  float4 u0 = p[0], u1 = p[1];
  f16x8 h;
  h[0] = (_Float16)u0.x; h[1] = (_Float16)u0.y;
  h[2] = (_Float16)u0.z; h[3] = (_Float16)u0.w;
  h[4] = (_Float16)u1.x; h[5] = (_Float16)u1.y;
  h[6] = (_Float16)u1.z; h[7] = (_Float16)u1.w;
  *((f16x8*)out + i) = h;
}

// ---- segment boundaries from sorted segment_ids ----
__global__ void segstart_kernel(const int* __restrict__ sid,
                                int* __restrict__ segstart, int total) {
  int i = blockIdx.x * blockDim.x + threadIdx.x;
  if (i >= total) return;
  int sg = sid[i];
  if (i == 0) segstart[0] = 0;
  else if (sid[i - 1] != sg) segstart[sg] = i;
  if (i == total - 1) segstart[sg + 1] = total;
}

// ---- fused GEMM + tanh + dot-with-v:  s[i] += sum_j tanh(X_i.W_j + bw_j) v_j
// tile 128x128, BK=64, XOR-swizzled LDS chunk placement (conflict-free b128)
__global__ __launch_bounds__(256) void gemm_s_kernel(
    const _Float16* __restrict__ X, const _Float16* __restrict__ W,
    const float* __restrict__ v, const float* __restrict__ bw,
    float* __restrict__ s) {
  __shared__ _Float16 As[128 * 64];   // 16 KB, [row][64], chunk-swizzled
  __shared__ _Float16 Bs[128 * 64];   // 16 KB
  const int rowBase = blockIdx.x * 128;
  const int jBase = blockIdx.y * 128;
  const int t = threadIdx.x;
  const int lane = t & 63;
  const int w = t >> 6;
  const int wm = w & 1, wn = w >> 1;

  f32x4 acc[4][4];
  const f32x4 zero = {0.f, 0.f, 0.f, 0.f};
#pragma unroll
  for (int i = 0; i < 4; ++i)
#pragma unroll
    for (int j = 0; j < 4; ++j) acc[i][j] = zero;

  for (int k0 = 0; k0 < DIM; k0 += 64) {
    __syncthreads();
#pragma unroll
    for (int q = 0; q < 4; ++q) {
      // LDS 16B-slot l holds global 16B chunk g = ((l&7) - row) & 7 of row l>>3
      int l = w * 256 + q * 64 + lane;
      int row = l >> 3;
      int g = ((l & 7) - row) & 7;
      load_lds16(X + (size_t)(rowBase + row) * DIM + k0 + g * 8,
                 &As[(size_t)(w * 256 + q * 64) * 8]);
      load_lds16(W + (size_t)(jBase + row) * DIM + k0 + g * 8,
                 &Bs[(size_t)(w * 256 + q * 64) * 8]);
    }
    __syncthreads();

    f16x8 a[2][4], b[2][4];
    const int kc = lane >> 4;  // which 16B chunk within a 32-wide k-step
#pragma unroll
    for (int s2 = 0; s2 < 2; ++s2) {
      int q = s2 * 4 + kc;
#pragma unroll
      for (int mt = 0; mt < 4; ++mt) {
        int row = wm * 64 + mt * 16 + (lane & 15);
        a[s2][mt] = *(const f16x8*)&As[row * 64 + ((q + row) & 7) * 8];
      }
#pragma unroll
      for (int nt = 0; nt < 4; ++nt) {
        int row = wn * 64 + nt * 16 + (lane & 15);
        b[s2][nt] = *(const f16x8*)&Bs[row * 64 + ((q + row) & 7) * 8];
      }
    }
#pragma unroll
    for (int s2 = 0; s2 < 2; ++s2)
#pragma unroll
      for (int mt = 0; mt < 4; ++mt)
#pragma unroll
        for (int nt = 0; nt < 4; ++nt)
          acc[mt][nt] = __builtin_amdgcn_mfma_f32_16x16x32_f16(
              a[s2][mt], b[s2][nt], acc[mt][nt], 0, 0, 0);
  }

  // epilogue: C/D layout col=lane&15, row=(lane>>4)*4+reg
  const int colBase = jBase + wn * 64 + (lane & 15);
  float vv[4], bb[4];
#pragma unroll
  for (int nt = 0; nt < 4; ++nt) {
    int j = colBase + nt * 16;
    vv[nt] = v[j];
    bb[nt] = bw[j];
  }
  const int g = lane >> 4;
#pragma unroll
  for (int mt = 0; mt < 4; ++mt) {
#pragma unroll
    for (int r = 0; r < 4; ++r) {
      float sumv = 0.f;
#pragma unroll
      for (int nt = 0; nt < 4; ++nt)
        sumv += tanh_fast(acc[mt][nt][r] + bb[nt]) * vv[nt];
      sumv += __shfl_xor(sumv, 1);
      sumv += __shfl_xor(sumv, 2);
      sumv += __shfl_xor(sumv, 4);
      sumv += __shfl_xor(sumv, 8);
      if ((lane & 15) == 0) {
        int row = rowBase + wm * 64 + mt * 16 + g * 4 + r;
        atomicAdd(&s[row], sumv);
      }
    }
  }
}

// ---- per-segment stable softmax -> att ----
__global__ void softmax_kernel(const float* __restrict__ s,
                               const int* __restrict__ segstart,
                               float* __restrict__ att) {
  int seg = blockIdx.x;
  int st = segstart[seg], en = segstart[seg + 1];
  int t = threadIdx.x;
  __shared__ float red[8];
  float m = -1e30f;
  for (int i = st + t; i < en; i += 256) m = fmaxf(m, s[i]);
  for (int d = 1; d < 64; d <<= 1) m = fmaxf(m, __shfl_xor(m, d));
  if ((t & 63) == 0) red[t >> 6] = m;
  __syncthreads();
  m = fmaxf(fmaxf(red[0], red[1]), fmaxf(red[2], red[3]));
  float z = 0.f;
  for (int i = st + t; i < en; i += 256) z += __expf(s[i] - m);
  for (int d = 1; d < 64; d <<= 1) z += __shfl_xor(z, d);
  if ((t & 63) == 0) red[4 + (t >> 6)] = z;
  __syncthreads();
  z = red[4] + red[5] + red[6] + red[7];
  float rz = 1.0f / z;
  for (int i = st + t; i < en; i += 256) att[i] = __expf(s[i] - m) * rz;
}

// ---- attention-weighted pooling, float4 + 4-way row-split + atomicAdd ----
// grid (128 segs, 4 row-parts), block 320 (thread t = float4 column t)
__global__ void pool_kernel(const float* __restrict__ F,
                            const float* __restrict__ att,
                            const int* __restrict__ segstart,
                            float* __restrict__ pooled) {
  int seg = blockIdx.x, part = blockIdx.y;
  int st = segstart[seg], en = segstart[seg + 1];
  int len = en - st;
  int chunk = (len + 3) >> 2;
  int r0 = st + chunk * part;
  int r1 = min(en, r0 + chunk);
  int t = threadIdx.x;
  f32x4 acc = {0.f, 0.f, 0.f, 0.f};
  int r = r0;
  for (; r + 2 <= r1; r += 2) {
    float a0 = att[r], a1 = att[r + 1];
    f32x4 f0 = ((const f32x4*)(F + (size_t)r * DIM))[t];
    f32x4 f1 = ((const f32x4*)(F + (size_t)(r + 1) * DIM))[t];
#pragma unroll
    for (int c = 0; c < 4; ++c) {
      acc[c] = fmaf(a0, f0[c], acc[c]);
      acc[c] = fmaf(a1, f1[c], acc[c]);
    }
  }
  if (r < r1) {
    float a0 = att[r];
    f32x4 f0 = ((const f32x4*)(F + (size_t)r * DIM))[t];
#pragma unroll
    for (int c = 0; c < 4; ++c) acc[c] = fmaf(a0, f0[c], acc[c]);
  }
  float* dst = pooled + (size_t)seg * DIM + t * 4;
#pragma unroll
  for (int c = 0; c < 4; ++c) atomicAdd(dst + c, acc[c]);
}

// ---- head layer 1: h = relu(pooled @ W1^T + b1), [128,512] ----
__global__ void head1_kernel(const float* __restrict__ pooled,
                             const float* __restrict__ W1,
                             const float* __restrict__ b1, float* __restrict__ h) {
  int og = blockIdx.x, sg = blockIdx.y;
  __shared__ float Wt[16 * 65];
  __shared__ float Pt[32 * 65];
  int t = threadIdx.x;
  int tx = t & 15, ty = t >> 4;
  float acc0 = 0.f, acc1 = 0.f;
  for (int kc = 0; kc < 20; ++kc) {
    __syncthreads();
#pragma unroll
    for (int u = 0; u < 4; ++u) {
      int lin = t + 256 * u;
      int o = lin >> 6, kk = lin & 63;
      Wt[o * 65 + kk] = W1[(size_t)(og * 16 + o) * DIM + kc * 64 + kk];
    }
#pragma unroll
    for (int u = 0; u < 8; ++u) {
      int lin = t + 256 * u;
      int ss = lin >> 6, kk = lin & 63;
      Pt[ss * 65 + kk] = pooled[(size_t)(sg * 32 + ss) * DIM + kc * 64 + kk];
    }
    __syncthreads();
#pragma unroll
    for (int kk = 0; kk < 64; ++kk) {
      float wv = Wt[tx * 65 + kk];
      acc0 = fmaf(Pt[ty * 65 + kk], wv, acc0);
      acc1 = fmaf(Pt[(ty + 16) * 65 + kk], wv, acc1);
    }
  }
  int o = og * 16 + tx;
  float bias = b1[o];
  h[(size_t)(sg * 32 + ty) * DHEAD + o] = fmaxf(acc0 + bias, 0.f);
  h[(size_t)(sg * 32 + ty + 16) * DHEAD + o] = fmaxf(acc1 + bias, 0.f);
}

// ---- head layer 2: out[seg] = relu_h[seg] . W2 + b2 ----
__global__ void head2_kernel(const float* __restrict__ h,
                             const float* __restrict__ W2,
                             const float* __restrict__ b2, float* __restrict__ out) {
  int seg = blockIdx.x;
  int t = threadIdx.x;
  float val = h[(size_t)seg * DHEAD + t] * W2[t] +
              h[(size_t)seg * DHEAD + t + 256] * W2[t + 256];
  for (int d = 1; d < 64; d <<= 1) val += __shfl_xor(val, d);
  __shared__ float red[4];
  if ((t & 63) == 0) red[t >> 6] = val;
  __syncthreads();
  if (t == 0) out[seg] = red[0] + red[1] + red[2] + red[3] + b2[0];
}

extern "C" void kernel_launch(void* const* d_in, const int* in_sizes, int n_in,
                              void* d_out, int out_size, void* d_ws, size_t ws_size,
                              hipStream_t stream) {
  const float* features = (const float*)d_in[0];
  const float* Ww = (const float*)d_in[1];
  const float* bw = (const float*)d_in[2];
  const float* v = (const float*)d_in[3];
  const float* W1 = (const float*)d_in[4];
  const float* b1 = (const float*)d_in[5];
  const float* W2 = (const float*)d_in[6];
  const float* b2 = (const float*)d_in[7];
  const int* segids = (const int*)d_in[8];
  float* out = (float*)d_out;

  char* ws = (char*)d_ws;
  _Float16* Xh = (_Float16*)(ws + OFF_XH);
  _Float16* Wh = (_Float16*)(ws + OFF_WH);
  float* s = (float*)(ws + OFF_S);
  float* att = (float*)(ws + OFF_ATT);
  int* segstart = (int*)(ws + OFF_SEG);
  float* pooled = (float*)(ws + OFF_POOL);
  float* h = (float*)(ws + OFF_H);

  // zero the atomic accumulators (ws is 0xAA-poisoned before every launch)
  hipMemsetAsync(s, 0, TOTAL_ROWS * sizeof(float), stream);
  hipMemsetAsync(pooled, 0, NSEG * DIM * sizeof(float), stream);

  cvt_f16_kernel<<<20480, 256, 0, stream>>>(features, Xh, TOTAL_ROWS * DIM / 8);
  cvt_f16_kernel<<<800, 256, 0, stream>>>(Ww, Wh, DIM * DIM / 8);
  segstart_kernel<<<TOTAL_ROWS / 256, 256, 0, stream>>>(segids, segstart, TOTAL_ROWS);

  dim3 ggrid(TOTAL_ROWS / 128, DIM / 128);
  gemm_s_kernel<<<ggrid, 256, 0, stream>>>(Xh, Wh, v, bw, s);

  softmax_kernel<<<NSEG, 256, 0, stream>>>(s, segstart, att);
  pool_kernel<<<dim3(NSEG, 4), 320, 0, stream>>>(features, att, segstart, pooled);
  head1_kernel<<<dim3(32, 4), 256, 0, stream>>>(pooled, W1, b1, h);
  head2_kernel<<<NSEG, 256, 0, stream>>>(h, W2, b2, out);
}